// Round 5
// baseline (787.421 us; speedup 1.0000x reference)
//
#include <hip/hip_runtime.h>
#include <math.h>

#define T_  4
#define B_  8
#define C1  128
#define C2  256
#define H_  128
#define W_  128
#define BN_EPS 1e-5f

// ---- workspace layout ----
// sp: packed spikes uint8 [B][131 rows][130 pix][128 ci], bits0-3 = t0..t3,
//     byte offset within 128-B pixel block swizzled: c ^ ((pix&7)<<4)
#define SP_BSTR  2179840ull              // 131*130*128
#define SP_SIZE  17438720ull             // 8 * SP_BSTR
#define AZ_OFF   SP_SIZE                 // [coblk8][tap9][kstep4][dig2][lane64][16B]
#define AZ_SIZE  589824ull
#define AR_OFF   (AZ_OFF + AZ_SIZE)      // [coblk8][kstep4][dig2][lane64][16B]
#define AR_SIZE  65536ull
#define PRM_OFF  (AR_OFF + AR_SIZE)      // [co256][4] f32: zmul,zoff,rmul,roff

// ---- LDS layout (156928 B, 1 block/CU) ----
#define LDS_AZ   0                       // 73728
#define LDS_RING 73728                   // 3 * 16640 = 49920
#define LDS_VST  123648                  // 32co x 128pix x {vz,vr} f32 = 32768
#define LDS_PRM  156416                  // 32co x 4 f32 = 512
#define LDS_TOT  156928

typedef __attribute__((ext_vector_type(4))) int i32x4;
typedef __attribute__((ext_vector_type(16))) int i32x16;

#define MF32(acc, A, Bv) acc = __builtin_amdgcn_mfma_i32_32x32x32_i8(A, Bv, acc, 0, 0, 0)

__global__ __launch_bounds__(256) void zero_ws_kernel(uint4* __restrict__ p, int n16) {
    int i = blockIdx.x * 256 + threadIdx.x;
    int stride = gridDim.x * 256;
    for (; i < n16; i += stride) p[i] = make_uint4(0u, 0u, 0u, 0u);
}

// Quantize weights to per-co 15-bit fixed point, split into 2 signed i8 digits,
// packed in 32x32x32 MFMA A-fragment order: lane = ((ci>>4)&1)*32 + (co&31),
// e = ci&15, kstep = ci>>5. Blocks 0-255: z (w1), 256-511: r (wr).
__global__ __launch_bounds__(256) void prep_kernel(
    const float* __restrict__ w1, const float* __restrict__ wr,
    const float* __restrict__ g1, const float* __restrict__ v1,
    const float* __restrict__ b1, const float* __restrict__ m1,
    const float* __restrict__ gr, const float* __restrict__ vr,
    const float* __restrict__ br, const float* __restrict__ mr,
    unsigned char* __restrict__ ws)
{
    __shared__ float red[256];
    const int tid = threadIdx.x;
    const bool is_r = blockIdx.x >= 256;
    const int co = blockIdx.x & 255;
    const int n = is_r ? 128 : 1152;
    const float* wsrc = is_r ? (wr + co * 128) : (w1 + co * 1152);

    float mx = 0.0f;
    for (int i = tid; i < n; i += 256) mx = fmaxf(mx, fabsf(wsrc[i]));
    red[tid] = mx;
    __syncthreads();
    for (int s = 128; s > 0; s >>= 1) {
        if (tid < s) red[tid] = fmaxf(red[tid], red[tid + s]);
        __syncthreads();
    }
    const float scale = red[0];
    const float qs = 32638.0f / scale;

    char* base = (char*)(ws + (is_r ? AR_OFF : AZ_OFF));
    const int coblk = co >> 5;
    const int corow = co & 31;
    for (int i = tid; i < n; i += 256) {
        const int wq = __float2int_rn(wsrc[i] * qs);
        const int d1 = ((wq + 128) & 255) - 128;
        const int d0 = (wq - d1) >> 8;
        int ci, tap;
        if (is_r) { ci = i; tap = 0; } else { ci = i / 9; tap = i - ci * 9; }
        const int kstep = ci >> 5;
        const int lane = ((ci >> 4) & 1) * 32 + corow;
        const int e = ci & 15;
        const int addr = is_r
            ? coblk * 8192  + ((kstep * 2) * 64 + lane) * 16 + e
            : coblk * 73728 + (((tap * 4 + kstep) * 2) * 64 + lane) * 16 + e;
        base[addr]        = (char)d0;
        base[addr + 1024] = (char)d1;
    }
    if (tid == 0) {
        float* prm = (float*)(ws + PRM_OFF);
        if (!is_r) {
            const float s1 = g1[co] * (1.0f / sqrtf(v1[co] + BN_EPS));
            prm[co * 4 + 0] = (scale / 32638.0f) * s1;
            prm[co * 4 + 1] = b1[co] - m1[co] * s1;
        } else {
            const float s2 = gr[co] * (1.0f / sqrtf(vr[co] + BN_EPS));
            prm[co * 4 + 2] = (scale / 32638.0f) * s2;
            prm[co * 4 + 3] = br[co] - mr[co] * s2;
        }
    }
}

// Stem: conv3x3 (2->128) + BN + LIF, writes packed (byte-swizzled) spikes.
__global__ __launch_bounds__(256) void stem_kernel(
    const float* __restrict__ x, const float* __restrict__ w0,
    const float* __restrict__ g0, const float* __restrict__ b0,
    const float* __restrict__ m0, const float* __restrict__ v0,
    unsigned char* __restrict__ sp)
{
    const int wseg = blockIdx.x;
    const int h    = blockIdx.y;
    const int b    = blockIdx.z;
    const int lane = threadIdx.x & 63;
    const int cg   = threadIdx.x >> 6;
    const int w    = wseg * 64 + lane;

    __shared__ float wl[2304];
    __shared__ float sc0s[128], m0s[128], b0s[128];

    for (int i = threadIdx.x; i < 2304; i += 256) wl[i] = w0[i];
    if (threadIdx.x < 128) {
        const int c = threadIdx.x;
        sc0s[c] = g0[c] * (1.0f / sqrtf(v0[c] + BN_EPS));
        m0s[c] = m0[c]; b0s[c] = b0[c];
    }
    __syncthreads();

    float xv[4][2][3][3];
#pragma unroll
    for (int t = 0; t < 4; ++t)
#pragma unroll
        for (int ci = 0; ci < 2; ++ci)
#pragma unroll
            for (int dh = 0; dh < 3; ++dh)
#pragma unroll
                for (int dw = 0; dw < 3; ++dw) {
                    const int hh = h + dh - 1, ww = w + dw - 1;
                    const bool ok = ((unsigned)hh < 128u) && ((unsigned)ww < 128u);
                    xv[t][ci][dh][dw] = ok ? x[(((size_t)(t * 8 + b) * 2 + ci) * 128 + hh) * 128 + ww] : 0.0f;
                }

    const int pix = w + 1;
    const int sw = (pix & 7) << 4;
    unsigned char* dst = sp + ((size_t)b * SP_BSTR) + ((size_t)((h + 1) * 130 + pix)) * 128;
    for (int i = 0; i < 8; ++i) {
        unsigned dwv = 0u;
#pragma unroll
        for (int j = 0; j < 4; ++j) {
            const int c = cg * 32 + i * 4 + j;
            float wreg[18];
#pragma unroll
            for (int k = 0; k < 18; ++k) wreg[k] = wl[c * 18 + k];
            const float sc = sc0s[c], mm = m0s[c], bb = b0s[c];
            float v = 0.0f; unsigned bits = 0u;
#pragma unroll
            for (int t = 0; t < 4; ++t) {
                float sum = 0.0f;
#pragma unroll
                for (int ci = 0; ci < 2; ++ci)
#pragma unroll
                    for (int dh = 0; dh < 3; ++dh)
#pragma unroll
                        for (int dw = 0; dw < 3; ++dw)
                            sum += xv[t][ci][dh][dw] * wreg[ci * 9 + dh * 3 + dw];
                const float y = (sum - mm) * sc + bb;
                v = v + (y - v) * 0.5f;
                if (v - 1.0f >= 0.0f) { bits |= 1u << t; v = 0.0f; }
            }
            dwv |= bits << (j * 8);
        }
        *(unsigned*)(dst + ((cg * 32 + i * 4) ^ sw)) = dwv;
    }
}

// Main fused kernel: conv3x3(z) + conv1x1(r) via mfma_i32_32x32x32_i8,
// BN + LIF, out = z_spike + r_spike. Block = 8 waves (4 wseg x 2 t-halves),
// covers 32 co x 128 w x 1 row x 4 t per pass, 8 passes. t01->t23 membrane
// state handed through LDS_VST. Full-128B-line output stores.
// Grid: (coblk 8, hstrip 16, b 8).
__global__ __launch_bounds__(512, 2) void main_i8_32(
    const unsigned char* __restrict__ ws, float* __restrict__ out)
{
    __shared__ __align__(16) char lds[LDS_TOT];

    const int coblk  = blockIdx.x;
    const int hstrip = blockIdx.y;
    const int b      = blockIdx.z;
    const int tid   = threadIdx.x;
    const int lane  = tid & 63;
    const int wid   = tid >> 6;
    const int thalf = wid & 1;
    const int wseg  = wid >> 1;
    const int l31   = lane & 31;
    const int lhi   = lane >> 5;
    const int wbase = wseg * 32;
    const int hfirst = hstrip * 8;
    const int pix0  = wbase + l31;
    const int tA    = thalf * 2;

    const unsigned char* spg = ws + (size_t)b * SP_BSTR;

    // stage A_z (72 KB) into LDS
    {
        const uint4* azg = (const uint4*)(ws + AZ_OFF + (size_t)coblk * 73728);
        uint4* azl = (uint4*)&lds[LDS_AZ];
        for (int i = tid; i < 4608; i += 512) azl[i] = azg[i];
    }
    // A_r fragments into registers
    i32x4 ar[4][2];
#pragma unroll
    for (int ks = 0; ks < 4; ++ks)
#pragma unroll
        for (int dg = 0; dg < 2; ++dg)
            ar[ks][dg] = *(const i32x4*)(ws + AR_OFF + coblk * 8192
                                         + (((ks * 2 + dg) * 64 + lane) << 4));
    // ring init: sp rows hfirst..hfirst+2 -> slot gr%3
    for (int i = tid; i < 3120; i += 512) {
        const int rr = i / 1040;
        const int off = (i - rr * 1040) * 16;
        const int gr = hfirst + rr;
        *(uint4*)&lds[LDS_RING + (gr % 3) * 16640 + off] =
            *(const uint4*)(spg + (size_t)gr * 16640 + off);
    }
    if (tid < 128)
        ((float*)&lds[LDS_PRM])[tid] = ((const float*)(ws + PRM_OFF))[coblk * 128 + tid];
    __syncthreads();

    for (int p = 0; p < 8; ++p) {
        const int h0 = hfirst + p;

        // prefetch next sp row (h0+3) into registers
        uint4 pf0, pf1, pf2;
        if (p < 7) {
            const uint4* src = (const uint4*)(spg + (size_t)(h0 + 3) * 16640);
            pf0 = src[tid];
            if (tid < 528) pf1 = src[tid + 512];
            if (tid < 16)  pf2 = src[tid + 1024];
        }

        int sl0 = h0 % 3;
        int sl1 = sl0 + 1; if (sl1 > 2) sl1 = 0;
        int sl2 = sl1 + 1; if (sl2 > 2) sl2 = 0;
        const int rbase[3] = { LDS_RING + sl0 * 16640, LDS_RING + sl1 * 16640,
                               LDS_RING + sl2 * 16640 };

        i32x16 za[2][2], ra[2][2];   // [t-local][digit]
#pragma unroll
        for (int tl = 0; tl < 2; ++tl)
#pragma unroll
            for (int dg = 0; dg < 2; ++dg) {
                za[tl][dg] = (i32x16)(0);
                ra[tl][dg] = (i32x16)(0);
            }

#pragma unroll
        for (int ks = 0; ks < 4; ++ks) {
#pragma unroll
            for (int kw = 0; kw < 3; ++kw) {
                i32x4 a0[3], a1[3];
#pragma unroll
                for (int kh = 0; kh < 3; ++kh) {
                    const int ab = LDS_AZ + ((kh * 3 + kw) * 4 + ks) * 2048 + lane * 16;
                    a0[kh] = *(const i32x4*)&lds[ab];
                    a1[kh] = *(const i32x4*)&lds[ab + 1024];
                }
                const int pix = pix0 + kw;
                const int pb = pix * 128 + ((ks * 32 + lhi * 16) ^ ((pix & 7) << 4));
#pragma unroll
                for (int rr = 0; rr < 3; ++rr) {
                    const uint4 d = *(const uint4*)&lds[rbase[rr] + pb];
#pragma unroll
                    for (int tl = 0; tl < 2; ++tl) {
                        const int t = tA + tl;
                        i32x4 bt;
                        bt[0] = (int)((d.x >> t) & 0x01010101u);
                        bt[1] = (int)((d.y >> t) & 0x01010101u);
                        bt[2] = (int)((d.z >> t) & 0x01010101u);
                        bt[3] = (int)((d.w >> t) & 0x01010101u);
                        MF32(za[tl][0], a0[rr], bt);
                        MF32(za[tl][1], a1[rr], bt);
                        if (kw == 1 && rr == 1) {
                            MF32(ra[tl][0], ar[ks][0], bt);
                            MF32(ra[tl][1], ar[ks][1], bt);
                        }
                    }
                }
            }
        }

        __syncthreads();   // b1: ring reads done, acc complete

        // commit prefetched row into slot sl0 (its reads finished at b1)
        if (p < 7) {
            uint4* dst = (uint4*)&lds[LDS_RING + sl0 * 16640];
            dst[tid] = pf0;
            if (tid < 528) dst[tid + 512] = pf1;
            if (tid < 16)  dst[tid + 1024] = pf2;
        }

        float yz2[16], yz3[16], yr2[16], yr3[16];
        float* opb = out + ((size_t)b * 256 + coblk * 32) * 16384
                         + (size_t)h0 * 128 + pix0;

        if (thalf == 0) {
            // t=0,1: BN + LIF, store, hand off membrane state
#pragma unroll
            for (int reg = 0; reg < 16; ++reg) {
                const int col = (reg & 3) + 8 * (reg >> 2) + 4 * lhi;
                const float4 pr = *(const float4*)&lds[LDS_PRM + col * 16];
                const float yz0 = fmaf((float)(za[0][0][reg] * 256 + za[0][1][reg]), pr.x, pr.y);
                const float yz1 = fmaf((float)(za[1][0][reg] * 256 + za[1][1][reg]), pr.x, pr.y);
                const float yr0 = fmaf((float)(ra[0][0][reg] * 256 + ra[0][1][reg]), pr.z, pr.w);
                const float yr1 = fmaf((float)(ra[1][0][reg] * 256 + ra[1][1][reg]), pr.z, pr.w);
                float vz = yz0 * 0.5f, vr = yr0 * 0.5f;
                float sz = 0.0f, sr = 0.0f;
                if (vz - 1.0f >= 0.0f) { sz = 1.0f; vz = 0.0f; }
                if (vr - 1.0f >= 0.0f) { sr = 1.0f; vr = 0.0f; }
                float* op = opb + (size_t)col * 16384;
                op[0] = sz + sr;
                vz = vz + (yz1 - vz) * 0.5f;
                vr = vr + (yr1 - vr) * 0.5f;
                sz = 0.0f; sr = 0.0f;
                if (vz - 1.0f >= 0.0f) { sz = 1.0f; vz = 0.0f; }
                if (vr - 1.0f >= 0.0f) { sr = 1.0f; vr = 0.0f; }
                op[33554432] = sz + sr;
                *(float2*)&lds[LDS_VST + (col * 128 + pix0) * 8] = make_float2(vz, vr);
            }
        } else {
            // t=2,3: combine digits + BN now; LIF after state arrives
#pragma unroll
            for (int reg = 0; reg < 16; ++reg) {
                const int col = (reg & 3) + 8 * (reg >> 2) + 4 * lhi;
                const float4 pr = *(const float4*)&lds[LDS_PRM + col * 16];
                yz2[reg] = fmaf((float)(za[0][0][reg] * 256 + za[0][1][reg]), pr.x, pr.y);
                yz3[reg] = fmaf((float)(za[1][0][reg] * 256 + za[1][1][reg]), pr.x, pr.y);
                yr2[reg] = fmaf((float)(ra[0][0][reg] * 256 + ra[0][1][reg]), pr.z, pr.w);
                yr3[reg] = fmaf((float)(ra[1][0][reg] * 256 + ra[1][1][reg]), pr.z, pr.w);
            }
        }

        __syncthreads();   // b2: vstate visible (also orders commit before next MFMA)

        if (thalf == 1) {
#pragma unroll
            for (int reg = 0; reg < 16; ++reg) {
                const int col = (reg & 3) + 8 * (reg >> 2) + 4 * lhi;
                const float2 vs = *(const float2*)&lds[LDS_VST + (col * 128 + pix0) * 8];
                float vz = vs.x + (yz2[reg] - vs.x) * 0.5f;
                float vr = vs.y + (yr2[reg] - vs.y) * 0.5f;
                float sz = 0.0f, sr = 0.0f;
                if (vz - 1.0f >= 0.0f) { sz = 1.0f; vz = 0.0f; }
                if (vr - 1.0f >= 0.0f) { sr = 1.0f; vr = 0.0f; }
                float* op = opb + (size_t)col * 16384;
                op[(size_t)2 * 33554432] = sz + sr;
                vz = vz + (yz3[reg] - vz) * 0.5f;
                vr = vr + (yr3[reg] - vr) * 0.5f;
                sz = 0.0f; sr = 0.0f;
                if (vz - 1.0f >= 0.0f) sz = 1.0f;
                if (vr - 1.0f >= 0.0f) sr = 1.0f;
                op[(size_t)3 * 33554432] = sz + sr;
            }
        }
    }
}

extern "C" void kernel_launch(void* const* d_in, const int* in_sizes, int n_in,
                              void* d_out, int out_size, void* d_ws, size_t ws_size,
                              hipStream_t stream) {
    const float* x  = (const float*)d_in[0];
    const float* w0 = (const float*)d_in[1];
    const float* g0 = (const float*)d_in[2];
    const float* b0 = (const float*)d_in[3];
    const float* m0 = (const float*)d_in[4];
    const float* v0 = (const float*)d_in[5];
    const float* w1 = (const float*)d_in[6];
    const float* g1 = (const float*)d_in[7];
    const float* b1 = (const float*)d_in[8];
    const float* m1 = (const float*)d_in[9];
    const float* v1 = (const float*)d_in[10];
    const float* wr = (const float*)d_in[11];
    const float* gr = (const float*)d_in[12];
    const float* br = (const float*)d_in[13];
    const float* mr = (const float*)d_in[14];
    const float* vr = (const float*)d_in[15];

    unsigned char* ws = (unsigned char*)d_ws;
    const int n16 = (int)(SP_SIZE / 16);

    zero_ws_kernel<<<dim3(2048), dim3(256), 0, stream>>>((uint4*)ws, n16);
    prep_kernel<<<dim3(512), dim3(256), 0, stream>>>(w1, wr, g1, v1, b1, m1, gr, vr, br, mr, ws);
    stem_kernel<<<dim3(2, 128, 8), dim3(256), 0, stream>>>(x, w0, g0, b0, m0, v0, ws);
    main_i8_32<<<dim3(8, 16, 8), dim3(512), 0, stream>>>(ws, (float*)d_out);
}